// Round 12
// baseline (676.293 us; speedup 1.0000x reference)
//
#include <hip/hip_runtime.h>
#include <hip/hip_bf16.h>
#include <cstdint>

// ---------------- problem constants ----------------
// B=2, S=2048, D=2048, H=16, HD=128, FF=8192; M = B*S = 4096 rows
constexpr float SCALE_QK = 0.02209708691207961f; // 1/sqrt(2048)
constexpr float LOG2E    = 1.4426950408889634f;

using short8 = __attribute__((ext_vector_type(8))) short;
using f32x4  = __attribute__((ext_vector_type(4))) float;
using ushort4v = __attribute__((ext_vector_type(4))) ushort;

#define MFMA16(a,b,c) __builtin_amdgcn_mfma_f32_16x16x32_bf16((a),(b),(c),0,0,0)

__device__ __forceinline__ ushort f2bf(float f){
  uint32_t u = __builtin_bit_cast(uint32_t, f);
  u += 0x7fffu + ((u >> 16) & 1u);      // RNE
  return (ushort)(u >> 16);
}

// async global->LDS, 16B per lane; LDS dest is wave-uniform base + lane*16
__device__ __forceinline__ void gload_lds16(const void* g, void* l){
  __builtin_amdgcn_global_load_lds(
      (const __attribute__((address_space(1))) void*)g,
      (__attribute__((address_space(3))) void*)l, 16, 0, 0);
}

// ---------------- LayerNorm: fp32 row -> bf16 row ----------------
__global__ __launch_bounds__(256) void ln_kernel(
    const float* __restrict__ x, const float* __restrict__ g,
    const float* __restrict__ sh, ushort* __restrict__ out){
  const int row = blockIdx.x, t = threadIdx.x;
  const float* xr = x + (size_t)row*2048 + t*8;
  float v[8];
  *(float4*)&v[0] = *(const float4*)(xr);
  *(float4*)&v[4] = *(const float4*)(xr + 4);
  float s = 0.f, sq = 0.f;
#pragma unroll
  for (int i = 0; i < 8; ++i){ s += v[i]; sq += v[i]*v[i]; }
#pragma unroll
  for (int d = 1; d < 64; d <<= 1){ s += __shfl_xor(s, d, 64); sq += __shfl_xor(sq, d, 64); }
  __shared__ float red[8];
  const int w = t >> 6, lane = t & 63;
  if (lane == 0){ red[w] = s; red[4 + w] = sq; }
  __syncthreads();
  s  = red[0] + red[1] + red[2] + red[3];
  sq = red[4] + red[5] + red[6] + red[7];
  const float mean = s * (1.f/2048.f);
  const float inv  = rsqrtf(sq * (1.f/2048.f) - mean*mean + 1e-5f);
  union { ushort u[8]; uint4 v4; } o;
#pragma unroll
  for (int i = 0; i < 8; ++i){
    int j = t*8 + i;
    o.u[i] = f2bf((v[i] - mean) * inv * g[j] + sh[j]);
  }
  *(uint4*)(out + (size_t)row*2048 + t*8) = o.v4;
}

// merged: four 2048x2048 fp32 [K][N] -> bf16 [N][K] (outputs contiguous)
__global__ __launch_bounds__(256) void wconv4(
    const float* __restrict__ w0, const float* __restrict__ w1p,
    const float* __restrict__ w2p, const float* __restrict__ w3p,
    ushort* __restrict__ out){
  __shared__ ushort tile[32][34];
  const int tx = threadIdx.x & 31, ty = threadIdx.x >> 5;
  const int n0 = blockIdx.x * 32, k0 = blockIdx.y * 32, z = blockIdx.z;
  const float* in = (z == 0) ? w0 : (z == 1) ? w1p : (z == 2) ? w2p : w3p;
  ushort* o = out + (size_t)z * 4194304;
#pragma unroll
  for (int r = 0; r < 4; ++r){
    int kk = ty + r*8;
    tile[kk][tx] = f2bf(in[(size_t)(k0 + kk)*2048 + n0 + tx]);
  }
  __syncthreads();
#pragma unroll
  for (int r = 0; r < 4; ++r){
    int nn = ty + r*8;
    o[(size_t)(n0 + nn)*2048 + k0 + tx] = tile[tx][nn];
  }
}

// merged FFN weight convert: z=0 -> w1 (K=2048,N=8192), z=1 -> w2 (K=8192,N=2048)
__global__ __launch_bounds__(256) void wconv_ffn(
    const float* __restrict__ w1, const float* __restrict__ w2,
    ushort* __restrict__ w1T, ushort* __restrict__ w2T){
  __shared__ ushort tile[32][34];
  const int tx = threadIdx.x & 31, ty = threadIdx.x >> 5;
  const int z = blockIdx.z;
  const float* in; ushort* out; int K, N, n0, k0;
  if (z == 0){ in = w1; out = w1T; K = 2048; N = 8192;
               n0 = blockIdx.x * 32; k0 = blockIdx.y * 32; }
  else       { in = w2; out = w2T; K = 8192; N = 2048;
               n0 = blockIdx.y * 32; k0 = blockIdx.x * 32; }
#pragma unroll
  for (int r = 0; r < 4; ++r){
    int kk = ty + r*8;
    tile[kk][tx] = f2bf(in[(size_t)(k0 + kk)*N + n0 + tx]);
  }
  __syncthreads();
#pragma unroll
  for (int r = 0; r < 4; ++r){
    int nn = ty + r*8;
    out[(size_t)(n0 + nn)*K + k0 + tx] = tile[tx][nn];
  }
}

// ---------------- 128x128 m97-structure GEMM ----------------
// EPI 0: fused-QKV, LDS-staged coalesced epilogue; q pre-scaled by
//        SCALE_QK*LOG2E (softmax runs in log2 domain); V -> V^T.
// EPI 1: fp32 = resid + bias + acc;  EPI 2: bf16 = gelu_tanh(acc + bias)
template<int EPI>
__global__ __launch_bounds__(256) void gemm_bt(
    const ushort* __restrict__ A, const ushort* __restrict__ Bt,
    int N, int K, void* __restrict__ outp,
    const float* __restrict__ resid, const float* __restrict__ bias){
  __shared__ ushort lds[2][128*64];
  const int tid = threadIdx.x, lane = tid & 63, wid = tid >> 6;
  const int wr = wid >> 1, wc = wid & 1;
  const int l15 = lane & 15, l4 = lane >> 4;

  const int bid = blockIdx.x;
  const int xcd = bid & 7, j = bid >> 3;
  const int mb = xcd*4 + (j & 3);
  const int nb = j >> 2;
  const int m0 = mb * 128, n0 = nb * 128;

  f32x4 acc[4][4];
#pragma unroll
  for (int mi = 0; mi < 4; ++mi)
#pragma unroll
    for (int ni = 0; ni < 4; ++ni) acc[mi][ni] = (f32x4){0.f,0.f,0.f,0.f};

  const ushort* Abase = A  + (size_t)m0*K;
  const ushort* Bbase = Bt + (size_t)n0*K;

  const int NTk = K >> 6;
  for (int kt = 0; kt < NTk; ++kt){
    if (kt) __syncthreads();
#pragma unroll
    for (int i = 0; i < 4; ++i){
      const int chunk = (i*4 + wid)*64 + lane;
      const int row = chunk >> 3;
      const int c8  = (chunk & 7) ^ (row & 7);
      const size_t goff = (size_t)row*K + (size_t)kt*64 + c8*8;
      gload_lds16(Abase + goff, (ushort*)&lds[0][0] + (size_t)(i*4 + wid)*512);
      gload_lds16(Bbase + goff, (ushort*)&lds[1][0] + (size_t)(i*4 + wid)*512);
    }
    __syncthreads();

#pragma unroll
    for (int kk = 0; kk < 2; ++kk){
      short8 af[4], bf[4];
      const int kb = kk*4 + l4;
#pragma unroll
      for (int i = 0; i < 4; ++i){
        const int rA = wr*64 + i*16 + l15;
        af[i] = *(const short8*)&lds[0][rA*64 + ((kb ^ (rA & 7))*8)];
        const int rB = wc*64 + i*16 + l15;
        bf[i] = *(const short8*)&lds[1][rB*64 + ((kb ^ (rB & 7))*8)];
      }
#pragma unroll
      for (int mi = 0; mi < 4; ++mi)
#pragma unroll
        for (int ni = 0; ni < 4; ++ni)
          acc[mi][ni] = MFMA16(af[mi], bf[ni], acc[mi][ni]);
    }
  }

  if constexpr (EPI == 0){
    __syncthreads();
    ushort* tile = (ushort*)&lds[0][0];
    const int which = n0 >> 11;
    const int hh = (n0 & 2047) >> 7;
    const int bb = m0 >> 11, srow0 = m0 & 2047;
    if (which != 2){
      const float qs = (which == 0) ? SCALE_QK * LOG2E : 1.0f; // log2-domain q
#pragma unroll
      for (int mi = 0; mi < 4; ++mi)
#pragma unroll
        for (int ni = 0; ni < 4; ++ni){
          const int rl = wr*64 + mi*16 + l4*4;
          const int cl = wc*64 + ni*16 + l15;
#pragma unroll
          for (int j2 = 0; j2 < 4; ++j2)
            tile[(rl + j2)*128 + cl] = f2bf(acc[mi][ni][j2] * qs);
        }
      __syncthreads();
      ushort* dst = (ushort*)outp + (size_t)which*8388608 +
                    ((size_t)(bb*16 + hh)*2048 + srow0)*128;
#pragma unroll
      for (int i = 0; i < 8; ++i){
        const int c = i*256 + tid, row = c >> 4, d8 = (c & 15)*8;
        *(uint4*)(dst + (size_t)row*128 + d8) = *(const uint4*)&tile[row*128 + d8];
      }
    } else {
#pragma unroll
      for (int mi = 0; mi < 4; ++mi)
#pragma unroll
        for (int ni = 0; ni < 4; ++ni){
          const int rl = wr*64 + mi*16 + l4*4;
          const int cl = wc*64 + ni*16 + l15;
          ushort4v o;
#pragma unroll
          for (int j2 = 0; j2 < 4; ++j2) o[j2] = f2bf(acc[mi][ni][j2]);
          *(ushort4v*)&tile[cl*128 + rl] = o;
        }
      __syncthreads();
      ushort* dst = (ushort*)outp + (size_t)2*8388608 +
                    (size_t)(bb*16 + hh)*262144 + srow0;
#pragma unroll
      for (int i = 0; i < 8; ++i){
        const int c = i*256 + tid, drow = c >> 4, s8 = (c & 15)*8;
        *(uint4*)(dst + (size_t)drow*2048 + s8) = *(const uint4*)&tile[drow*128 + s8];
      }
    }
  } else {
#pragma unroll
    for (int mi = 0; mi < 4; ++mi){
#pragma unroll
      for (int ni = 0; ni < 4; ++ni){
        const int rloc = wr*64 + mi*16 + l4*4;
        const int col  = n0 + wc*64 + ni*16 + l15;
#pragma unroll
        for (int j2 = 0; j2 < 4; ++j2){
          const int m = m0 + rloc + j2;
          float v = acc[mi][ni][j2];
          if constexpr (EPI == 1){
            ((float*)outp)[(size_t)m*N + col] = resid[(size_t)m*N + col] + bias[col] + v;
          } else {
            const float xx = v + bias[col];
            const float z  = 0.7978845608f*(xx + 0.044715f*xx*xx*xx);
            const float t  = __expf(-2.f*fabsf(z));
            const float th = (1.f - t)/(1.f + t);
            const float gl = 0.5f*xx*(1.f + copysignf(th, xx));
            ((ushort*)outp)[(size_t)m*N + col] = f2bf(gl);
          }
        }
      }
    }
  }
}

// ---------------- causal flash attention, QBLK=128, 8 waves ----------------
// 512 thr = 8 waves; wave w owns 16 q-rows (w*16). Same 80KB LDS -> still
// 2 blocks/CU but 16 waves/CU (was 8): doubled TLP for the latency-bound
// per-tile chain. Lazy defer-max (zero shuffles common path) kept.
__global__ __launch_bounds__(512, 2) void attn_kernel(
    const ushort* __restrict__ q, const ushort* __restrict__ k,
    const ushort* __restrict__ vt, ushort* __restrict__ ctx){
  __shared__ ushort k_lds[2][64*128];   // 32 KB
  __shared__ ushort v_lds[2][128*64];   // 32 KB  [d][kv]
  __shared__ ushort p_lds[8][16*64];    // 16 KB  per-wave P
  const int tid = threadIdx.x, lane = tid & 63, w = tid >> 6;
  const int l15 = lane & 15, l4 = lane >> 4;
  const int id = blockIdx.x;
  const int bh = id & 31;
  const int r  = id >> 5;
  const int qt = (r < 8) ? (15 - r) : (r - 8);
  const int bb = bh >> 4, hh = bh & 15;
  const ushort* kbase = k  + (size_t)bh * 262144;
  const ushort* vbase = vt + (size_t)bh * 262144;

  // Q fragments: wave w rows qt*128 + w*16 + l15
  short8 qf[4];
  {
    const int s = qt*128 + w*16 + l15;
    const ushort* qr = q + ((size_t)bh*2048 + s)*128 + l4*8;
#pragma unroll
    for (int kk = 0; kk < 4; ++kk) qf[kk] = *(const short8*)(qr + kk*32);
  }

  f32x4 cacc[8];
#pragma unroll
  for (int dt = 0; dt < 8; ++dt) cacc[dt] = (f32x4){0.f,0.f,0.f,0.f};
  float mrun[4], lrun[4];
#pragma unroll
  for (int j = 0; j < 4; ++j){ mrun[j] = -1e30f; lrun[j] = 0.f; }

  // stage K tile (64x128) + V^T tile (128x64); 8 waves x 2 iters each
  auto stage = [&](int buf, int t){
    const ushort* ksrc = kbase + (size_t)t*8192;
#pragma unroll
    for (int i = 0; i < 2; ++i){
      const int base = i*512 + w*64;
      const int chunk = base + lane;
      const int kr = chunk >> 4;
      const int c8 = (chunk & 15) ^ (kr & 7);
      gload_lds16(ksrc + (size_t)kr*128 + c8*8, &k_lds[buf][(size_t)base*8]);
    }
#pragma unroll
    for (int i = 0; i < 2; ++i){
      const int base = i*512 + w*64;
      const int chunk = base + lane;
      const int vr = chunk >> 3;
      const int c8 = (chunk & 7) ^ (vr & 7);
      gload_lds16(vbase + (size_t)vr*2048 + t*64 + c8*8, &v_lds[buf][(size_t)base*8]);
    }
  };

  const int nt = 2*qt + 2;
  stage(0, 0);
  __syncthreads();
  int cur = 0;
  for (int t = 0; t < nt; ++t){
    if (t + 1 < nt) stage(cur ^ 1, t + 1);

    // second diag tile fully masked for waves 0-3 (rows < 64)
    const bool skip = (t == 2*qt + 1) && (w < 4);
    if (!skip){
      f32x4 sa[4];
#pragma unroll
      for (int ct = 0; ct < 4; ++ct) sa[ct] = (f32x4){0.f,0.f,0.f,0.f};
      __builtin_amdgcn_s_setprio(1);
#pragma unroll
      for (int kk = 0; kk < 4; ++kk){
#pragma unroll
        for (int ct = 0; ct < 4; ++ct){
          const int kr = ct*16 + l15;
          short8 kf = *(const short8*)&k_lds[cur][kr*128 + (((kk*4 + l4) ^ (kr & 7))*8)];
          sa[ct] = MFMA16(qf[kk], kf, sa[ct]);
        }
      }
      __builtin_amdgcn_s_setprio(0);

      const bool anymask = (t >= 2*qt) && !((t == 2*qt) && (w >= 4));
      // lane-local masked max per row; wave-wide lazy trigger
      float rowlm[4];
      bool over = false;
#pragma unroll
      for (int j = 0; j < 4; ++j){
        const int qa = qt*128 + w*16 + l4*4 + j;
        float lm = -1e30f;
#pragma unroll
        for (int ct = 0; ct < 4; ++ct){
          float sc = sa[ct][j];
          if (anymask){
            const int ka = t*64 + ct*16 + l15;
            sc = (ka > qa) ? -1e30f : sc;
          }
          sa[ct][j] = sc;
          lm = fmaxf(lm, sc);
        }
        rowlm[j] = lm;
        over = over || (lm > mrun[j] + 8.f);
      }
      if (__any(over)){  // rare: full rowmax reduce + rescale
#pragma unroll
        for (int j = 0; j < 4; ++j){
          float mx = rowlm[j];
#pragma unroll
          for (int d = 1; d < 16; d <<= 1) mx = fmaxf(mx, __shfl_xor(mx, d, 16));
          const float mnew = fmaxf(mrun[j], mx);
          const float corr = exp2f(mrun[j] - mnew);
          mrun[j] = mnew; lrun[j] *= corr;
#pragma unroll
          for (int dt = 0; dt < 8; ++dt) cacc[dt][j] *= corr;
        }
      }
      // P = exp2(s - m), row sums (lane-local)
#pragma unroll
      for (int j = 0; j < 4; ++j){
        float psum = 0.f;
#pragma unroll
        for (int ct = 0; ct < 4; ++ct){
          const float p = exp2f(sa[ct][j] - mrun[j]);
          sa[ct][j] = p; psum += p;
        }
        lrun[j] += psum;
      }

      // P -> bf16 LDS (wave-private), [row 16][kv 64] swizzled
#pragma unroll
      for (int ct = 0; ct < 4; ++ct)
#pragma unroll
        for (int j = 0; j < 4; ++j){
          const int row = l4*4 + j, col = ct*16 + l15;
          p_lds[w][row*64 + ((col >> 3) ^ (row & 7))*8 + (col & 7)] = f2bf(sa[ct][j]);
        }

      // PV: ctx[16][128] += P[16][64] * V[64][128]
      __builtin_amdgcn_s_setprio(1);
#pragma unroll
      for (int kk2 = 0; kk2 < 2; ++kk2){
        const int kb = kk2*4 + l4;
        short8 pa = *(const short8*)&p_lds[w][l15*64 + ((kb ^ (l15 & 7))*8)];
#pragma unroll
        for (int dt = 0; dt < 8; ++dt){
          const int vr = dt*16 + l15;
          short8 vf = *(const short8*)&v_lds[cur][vr*64 + ((kb ^ (vr & 7))*8)];
          cacc[dt] = MFMA16(pa, vf, cacc[dt]);
        }
      }
      __builtin_amdgcn_s_setprio(0);
    }

    if (t + 1 < nt){ __syncthreads(); cur ^= 1; }
  }

  // epilogue
  float inv[4];
#pragma unroll
  for (int j = 0; j < 4; ++j){
    float lt = lrun[j];
#pragma unroll
    for (int d = 1; d < 16; d <<= 1) lt += __shfl_xor(lt, d, 16);
    inv[j] = 1.f / lt;
  }
#pragma unroll
  for (int dt = 0; dt < 8; ++dt)
#pragma unroll
    for (int j = 0; j < 4; ++j){
      const int s = qt*128 + w*16 + l4*4 + j;
      const int d = dt*16 + l15;
      ctx[((size_t)(bb*2048 + s))*2048 + hh*128 + d] = f2bf(cacc[dt][j] * inv[j]);
    }
}

// ---------------- launch ----------------
extern "C" void kernel_launch(void* const* d_in, const int* in_sizes, int n_in,
                              void* d_out, int out_size, void* d_ws, size_t ws_size,
                              hipStream_t stream) {
  const float* x  = (const float*)d_in[0];
  const float* wq = (const float*)d_in[1];
  const float* wk = (const float*)d_in[2];
  const float* wv = (const float*)d_in[3];
  const float* wo = (const float*)d_in[4];
  const float* bo = (const float*)d_in[5];
  const float* g1 = (const float*)d_in[6];
  const float* s1 = (const float*)d_in[7];
  const float* g2 = (const float*)d_in[8];
  const float* s2 = (const float*)d_in[9];
  const float* w1 = (const float*)d_in[10];
  const float* b1 = (const float*)d_in[11];
  const float* w2 = (const float*)d_in[12];
  const float* b2 = (const float*)d_in[13];
  float* out = (float*)d_out;
  char* ws = (char*)d_ws;

  // workspace layout (bytes)
  ushort* wqkvT = (ushort*)(ws + 0);         // [6144][2048] + woT contiguous after
  ushort* woT = (ushort*)(ws + 25165824);
  ushort* w1T = (ushort*)(ws + 33554432);    // [8192][2048]
  ushort* w2T = (ushort*)(ws + 67108864);    // [2048][8192]
  ushort* h1  = (ushort*)(ws + 100663296);   // [4096][2048]
  ushort* qb  = (ushort*)(ws + 117440512);   // [32][2048][128]; k, v^T follow
  ushort* kb  = (ushort*)(ws + 134217728);   // [32][2048][128]
  ushort* vtb = (ushort*)(ws + 150994944);   // [32][128][2048] (V^T, by QKV epi)
  ushort* ctxb= (ushort*)(ws + 184549376);   // [4096][2048]
  float*  x2  = (float*)(ws + 201326592);    // [4096][2048] fp32
  ushort* h2  = (ushort*)(ws + 234881024);   // [4096][2048]
  ushort* ffb = (ushort*)(ws + 117440512);   // [4096][8192] aliases q/k/vt

  // weights -> bf16 transposed
  wconv4<<<dim3(64, 64, 4), 256, 0, stream>>>(wq, wk, wv, wo, wqkvT);
  wconv_ffn<<<dim3(256, 64, 2), 256, 0, stream>>>(w1, w2, w1T, w2T);

  // LN1
  ln_kernel<<<4096, 256, 0, stream>>>(x, g1, s1, h1);

  // fused QKV: q (pre-scaled by SCALE*log2e), k -> [b,h,s,d]; V -> V^T
  gemm_bt<0><<<32*48, 256, 0, stream>>>(h1, wqkvT, 6144, 2048, qb, nullptr, nullptr);

  // attention (8-wave blocks; XCD-pinned bh; work-paired qt order)
  attn_kernel<<<512, 512, 0, stream>>>(qb, kb, vtb, ctxb);

  // out proj + residual -> x2 (fp32)
  gemm_bt<1><<<32*16, 256, 0, stream>>>(ctxb, woT, 2048, 2048, x2, x, bo);

  // LN2
  ln_kernel<<<4096, 256, 0, stream>>>(x2, g2, s2, h2);

  // FFN (both m97 gemm_bt)
  gemm_bt<2><<<32*64, 256, 0, stream>>>(h2, w1T, 8192, 2048, ffb, nullptr, b1);
  gemm_bt<1><<<32*16, 256, 0, stream>>>(ffb, w2T, 2048, 8192, out, x2, b2);

  (void)in_sizes; (void)n_in; (void)out_size; (void)ws_size;
}

// Round 13
// 668.923 us; speedup vs baseline: 1.0110x; 1.0110x over previous
//
#include <hip/hip_runtime.h>
#include <hip/hip_bf16.h>
#include <cstdint>

// ---------------- problem constants ----------------
// B=2, S=2048, D=2048, H=16, HD=128, FF=8192; M = B*S = 4096 rows
constexpr float SCALE_QK = 0.02209708691207961f; // 1/sqrt(2048)
constexpr float LOG2E    = 1.4426950408889634f;

using short8 = __attribute__((ext_vector_type(8))) short;
using f32x4  = __attribute__((ext_vector_type(4))) float;
using ushort4v = __attribute__((ext_vector_type(4))) ushort;

#define MFMA16(a,b,c) __builtin_amdgcn_mfma_f32_16x16x32_bf16((a),(b),(c),0,0,0)

__device__ __forceinline__ ushort f2bf(float f){
  uint32_t u = __builtin_bit_cast(uint32_t, f);
  u += 0x7fffu + ((u >> 16) & 1u);      // RNE
  return (ushort)(u >> 16);
}

// async global->LDS, 16B per lane; LDS dest is wave-uniform base + lane*16
__device__ __forceinline__ void gload_lds16(const void* g, void* l){
  __builtin_amdgcn_global_load_lds(
      (const __attribute__((address_space(1))) void*)g,
      (__attribute__((address_space(3))) void*)l, 16, 0, 0);
}

// ---------------- LayerNorm: fp32 row -> bf16 row ----------------
__global__ __launch_bounds__(256) void ln_kernel(
    const float* __restrict__ x, const float* __restrict__ g,
    const float* __restrict__ sh, ushort* __restrict__ out){
  const int row = blockIdx.x, t = threadIdx.x;
  const float* xr = x + (size_t)row*2048 + t*8;
  float v[8];
  *(float4*)&v[0] = *(const float4*)(xr);
  *(float4*)&v[4] = *(const float4*)(xr + 4);
  float s = 0.f, sq = 0.f;
#pragma unroll
  for (int i = 0; i < 8; ++i){ s += v[i]; sq += v[i]*v[i]; }
#pragma unroll
  for (int d = 1; d < 64; d <<= 1){ s += __shfl_xor(s, d, 64); sq += __shfl_xor(sq, d, 64); }
  __shared__ float red[8];
  const int w = t >> 6, lane = t & 63;
  if (lane == 0){ red[w] = s; red[4 + w] = sq; }
  __syncthreads();
  s  = red[0] + red[1] + red[2] + red[3];
  sq = red[4] + red[5] + red[6] + red[7];
  const float mean = s * (1.f/2048.f);
  const float inv  = rsqrtf(sq * (1.f/2048.f) - mean*mean + 1e-5f);
  union { ushort u[8]; uint4 v4; } o;
#pragma unroll
  for (int i = 0; i < 8; ++i){
    int j = t*8 + i;
    o.u[i] = f2bf((v[i] - mean) * inv * g[j] + sh[j]);
  }
  *(uint4*)(out + (size_t)row*2048 + t*8) = o.v4;
}

// merged: four 2048x2048 fp32 [K][N] -> bf16 [N][K] (outputs contiguous)
__global__ __launch_bounds__(256) void wconv4(
    const float* __restrict__ w0, const float* __restrict__ w1p,
    const float* __restrict__ w2p, const float* __restrict__ w3p,
    ushort* __restrict__ out){
  __shared__ ushort tile[32][34];
  const int tx = threadIdx.x & 31, ty = threadIdx.x >> 5;
  const int n0 = blockIdx.x * 32, k0 = blockIdx.y * 32, z = blockIdx.z;
  const float* in = (z == 0) ? w0 : (z == 1) ? w1p : (z == 2) ? w2p : w3p;
  ushort* o = out + (size_t)z * 4194304;
#pragma unroll
  for (int r = 0; r < 4; ++r){
    int kk = ty + r*8;
    tile[kk][tx] = f2bf(in[(size_t)(k0 + kk)*2048 + n0 + tx]);
  }
  __syncthreads();
#pragma unroll
  for (int r = 0; r < 4; ++r){
    int nn = ty + r*8;
    o[(size_t)(n0 + nn)*2048 + k0 + tx] = tile[tx][nn];
  }
}

// merged FFN weight convert: z=0 -> w1 (K=2048,N=8192), z=1 -> w2 (K=8192,N=2048)
__global__ __launch_bounds__(256) void wconv_ffn(
    const float* __restrict__ w1, const float* __restrict__ w2,
    ushort* __restrict__ w1T, ushort* __restrict__ w2T){
  __shared__ ushort tile[32][34];
  const int tx = threadIdx.x & 31, ty = threadIdx.x >> 5;
  const int z = blockIdx.z;
  const float* in; ushort* out; int K, N, n0, k0;
  if (z == 0){ in = w1; out = w1T; K = 2048; N = 8192;
               n0 = blockIdx.x * 32; k0 = blockIdx.y * 32; }
  else       { in = w2; out = w2T; K = 8192; N = 2048;
               n0 = blockIdx.y * 32; k0 = blockIdx.x * 32; }
#pragma unroll
  for (int r = 0; r < 4; ++r){
    int kk = ty + r*8;
    tile[kk][tx] = f2bf(in[(size_t)(k0 + kk)*N + n0 + tx]);
  }
  __syncthreads();
#pragma unroll
  for (int r = 0; r < 4; ++r){
    int nn = ty + r*8;
    out[(size_t)(n0 + nn)*K + k0 + tx] = tile[tx][nn];
  }
}

// ---------------- 128x128 m97-structure GEMM ----------------
// MODE 0: mb = xcd*4 + (j&3)  (A panel set 2MB/XCD; for K<=2048 shapes)
// MODE 1: 2 m-panels/XCD in super-rounds (A set 4MB = L2; for K=8192/FFN2,
//         N must be 2048 -> 16 n-tiles)
// EPI 0: fused-QKV, LDS-staged coalesced epilogue; q pre-scaled by
//        SCALE_QK*LOG2E (softmax runs in log2 domain); V -> V^T.
// EPI 1: fp32 = resid + bias + acc;  EPI 2: bf16 = gelu_tanh(acc + bias)
template<int EPI, int MODE>
__global__ __launch_bounds__(256) void gemm_bt(
    const ushort* __restrict__ A, const ushort* __restrict__ Bt,
    int N, int K, void* __restrict__ outp,
    const float* __restrict__ resid, const float* __restrict__ bias){
  __shared__ ushort lds[2][128*64];
  const int tid = threadIdx.x, lane = tid & 63, wid = tid >> 6;
  const int wr = wid >> 1, wc = wid & 1;
  const int l15 = lane & 15, l4 = lane >> 4;

  const int bid = blockIdx.x;
  const int xcd = bid & 7, j = bid >> 3;
  int mb, nb;
  if constexpr (MODE == 0){
    mb = xcd*4 + (j & 3); nb = j >> 2;
  } else {
    const int jm = j & 1, rest = j >> 1;
    nb = rest & 15;
    mb = (rest >> 4)*16 + xcd*2 + jm;
  }
  const int m0 = mb * 128, n0 = nb * 128;

  f32x4 acc[4][4];
#pragma unroll
  for (int mi = 0; mi < 4; ++mi)
#pragma unroll
    for (int ni = 0; ni < 4; ++ni) acc[mi][ni] = (f32x4){0.f,0.f,0.f,0.f};

  const ushort* Abase = A  + (size_t)m0*K;
  const ushort* Bbase = Bt + (size_t)n0*K;

  const int NTk = K >> 6;
  for (int kt = 0; kt < NTk; ++kt){
    if (kt) __syncthreads();
#pragma unroll
    for (int i = 0; i < 4; ++i){
      const int chunk = (i*4 + wid)*64 + lane;
      const int row = chunk >> 3;
      const int c8  = (chunk & 7) ^ (row & 7);
      const size_t goff = (size_t)row*K + (size_t)kt*64 + c8*8;
      gload_lds16(Abase + goff, (ushort*)&lds[0][0] + (size_t)(i*4 + wid)*512);
      gload_lds16(Bbase + goff, (ushort*)&lds[1][0] + (size_t)(i*4 + wid)*512);
    }
    __syncthreads();

#pragma unroll
    for (int kk = 0; kk < 2; ++kk){
      short8 af[4], bf[4];
      const int kb = kk*4 + l4;
#pragma unroll
      for (int i = 0; i < 4; ++i){
        const int rA = wr*64 + i*16 + l15;
        af[i] = *(const short8*)&lds[0][rA*64 + ((kb ^ (rA & 7))*8)];
        const int rB = wc*64 + i*16 + l15;
        bf[i] = *(const short8*)&lds[1][rB*64 + ((kb ^ (rB & 7))*8)];
      }
#pragma unroll
      for (int mi = 0; mi < 4; ++mi)
#pragma unroll
        for (int ni = 0; ni < 4; ++ni)
          acc[mi][ni] = MFMA16(af[mi], bf[ni], acc[mi][ni]);
    }
  }

  if constexpr (EPI == 0){
    __syncthreads();
    ushort* tile = (ushort*)&lds[0][0];
    const int which = n0 >> 11;
    const int hh = (n0 & 2047) >> 7;
    const int bb = m0 >> 11, srow0 = m0 & 2047;
    if (which != 2){
      const float qs = (which == 0) ? SCALE_QK * LOG2E : 1.0f; // log2-domain q
#pragma unroll
      for (int mi = 0; mi < 4; ++mi)
#pragma unroll
        for (int ni = 0; ni < 4; ++ni){
          const int rl = wr*64 + mi*16 + l4*4;
          const int cl = wc*64 + ni*16 + l15;
#pragma unroll
          for (int j2 = 0; j2 < 4; ++j2)
            tile[(rl + j2)*128 + cl] = f2bf(acc[mi][ni][j2] * qs);
        }
      __syncthreads();
      ushort* dst = (ushort*)outp + (size_t)which*8388608 +
                    ((size_t)(bb*16 + hh)*2048 + srow0)*128;
#pragma unroll
      for (int i = 0; i < 8; ++i){
        const int c = i*256 + tid, row = c >> 4, d8 = (c & 15)*8;
        *(uint4*)(dst + (size_t)row*128 + d8) = *(const uint4*)&tile[row*128 + d8];
      }
    } else {
#pragma unroll
      for (int mi = 0; mi < 4; ++mi)
#pragma unroll
        for (int ni = 0; ni < 4; ++ni){
          const int rl = wr*64 + mi*16 + l4*4;
          const int cl = wc*64 + ni*16 + l15;
          ushort4v o;
#pragma unroll
          for (int j2 = 0; j2 < 4; ++j2) o[j2] = f2bf(acc[mi][ni][j2]);
          *(ushort4v*)&tile[cl*128 + rl] = o;
        }
      __syncthreads();
      ushort* dst = (ushort*)outp + (size_t)2*8388608 +
                    (size_t)(bb*16 + hh)*262144 + srow0;
#pragma unroll
      for (int i = 0; i < 8; ++i){
        const int c = i*256 + tid, drow = c >> 4, s8 = (c & 15)*8;
        *(uint4*)(dst + (size_t)drow*2048 + s8) = *(const uint4*)&tile[drow*128 + s8];
      }
    }
  } else {
#pragma unroll
    for (int mi = 0; mi < 4; ++mi){
#pragma unroll
      for (int ni = 0; ni < 4; ++ni){
        const int rloc = wr*64 + mi*16 + l4*4;
        const int col  = n0 + wc*64 + ni*16 + l15;
#pragma unroll
        for (int j2 = 0; j2 < 4; ++j2){
          const int m = m0 + rloc + j2;
          float v = acc[mi][ni][j2];
          if constexpr (EPI == 1){
            ((float*)outp)[(size_t)m*N + col] = resid[(size_t)m*N + col] + bias[col] + v;
          } else {
            const float xx = v + bias[col];
            const float z  = 0.7978845608f*(xx + 0.044715f*xx*xx*xx);
            const float t  = __expf(-2.f*fabsf(z));
            const float th = (1.f - t)/(1.f + t);
            const float gl = 0.5f*xx*(1.f + copysignf(th, xx));
            ((ushort*)outp)[(size_t)m*N + col] = f2bf(gl);
          }
        }
      }
    }
  }
}

// ---------------- causal flash attention, QBLK=128 (R11 best) ----------------
// log2-domain softmax + LAZY defer-max: common path has ZERO cross-lane
// shuffles (lane-local 4-val max + one __any); full reduce + rescale only
// when some row's max grows by >8 log2-units.
__global__ __launch_bounds__(256, 2) void attn_kernel(
    const ushort* __restrict__ q, const ushort* __restrict__ k,
    const ushort* __restrict__ vt, ushort* __restrict__ ctx){
  __shared__ ushort k_lds[2][64*128];
  __shared__ ushort v_lds[2][128*64];
  __shared__ ushort p_lds[4][32*64];
  const int tid = threadIdx.x, lane = tid & 63, w = tid >> 6;
  const int l15 = lane & 15, l4 = lane >> 4;
  const int id = blockIdx.x;
  const int bh = id & 31;
  const int r  = id >> 5;
  const int qt = (r < 8) ? (15 - r) : (r - 8);
  const int bb = bh >> 4, hh = bh & 15;
  const ushort* kbase = k  + (size_t)bh * 262144;
  const ushort* vbase = vt + (size_t)bh * 262144;

  short8 qf[2][4];
#pragma unroll
  for (int mi = 0; mi < 2; ++mi){
    const int s = qt*128 + w*32 + mi*16 + l15;
    const ushort* qr = q + ((size_t)bh*2048 + s)*128 + l4*8;
#pragma unroll
    for (int kk = 0; kk < 4; ++kk) qf[mi][kk] = *(const short8*)(qr + kk*32);
  }

  f32x4 cacc[2][8];
#pragma unroll
  for (int mi = 0; mi < 2; ++mi)
#pragma unroll
    for (int dt = 0; dt < 8; ++dt) cacc[mi][dt] = (f32x4){0.f,0.f,0.f,0.f};
  float mrun[2][4], lrun[2][4];
#pragma unroll
  for (int mi = 0; mi < 2; ++mi)
#pragma unroll
    for (int j = 0; j < 4; ++j){ mrun[mi][j] = -1e30f; lrun[mi][j] = 0.f; }

  auto stage = [&](int buf, int t){
    const ushort* ksrc = kbase + (size_t)t*8192;
#pragma unroll
    for (int i = 0; i < 4; ++i){
      const int base = i*256 + w*64;
      const int chunk = base + lane;
      const int kr = chunk >> 4;
      const int c8 = (chunk & 15) ^ (kr & 7);
      gload_lds16(ksrc + (size_t)kr*128 + c8*8, &k_lds[buf][(size_t)base*8]);
    }
#pragma unroll
    for (int i = 0; i < 4; ++i){
      const int base = i*256 + w*64;
      const int chunk = base + lane;
      const int vr = chunk >> 3;
      const int c8 = (chunk & 7) ^ (vr & 7);
      gload_lds16(vbase + (size_t)vr*2048 + t*64 + c8*8, &v_lds[buf][(size_t)base*8]);
    }
  };

  const int nt = 2*qt + 2;
  stage(0, 0);
  __syncthreads();
  int cur = 0;
  for (int t = 0; t < nt; ++t){
    if (t + 1 < nt) stage(cur ^ 1, t + 1);

    const bool skip = (t == 2*qt + 1) && (w < 2);
    if (!skip){
      f32x4 sa[2][4];
#pragma unroll
      for (int mi = 0; mi < 2; ++mi)
#pragma unroll
        for (int ct = 0; ct < 4; ++ct) sa[mi][ct] = (f32x4){0.f,0.f,0.f,0.f};
      __builtin_amdgcn_s_setprio(1);
#pragma unroll
      for (int kk = 0; kk < 4; ++kk){
#pragma unroll
        for (int ct = 0; ct < 4; ++ct){
          const int kr = ct*16 + l15;
          short8 kf = *(const short8*)&k_lds[cur][kr*128 + (((kk*4 + l4) ^ (kr & 7))*8)];
          sa[0][ct] = MFMA16(qf[0][kk], kf, sa[0][ct]);
          sa[1][ct] = MFMA16(qf[1][kk], kf, sa[1][ct]);
        }
      }
      __builtin_amdgcn_s_setprio(0);

      const bool anymask = (t >= 2*qt) && !((t == 2*qt) && (w >= 2));
      float rowlm[2][4];
      bool over = false;
#pragma unroll
      for (int mi = 0; mi < 2; ++mi){
#pragma unroll
        for (int j = 0; j < 4; ++j){
          const int qa = qt*128 + w*32 + mi*16 + l4*4 + j;
          float lm = -1e30f;
#pragma unroll
          for (int ct = 0; ct < 4; ++ct){
            float sc = sa[mi][ct][j];
            if (anymask){
              const int ka = t*64 + ct*16 + l15;
              sc = (ka > qa) ? -1e30f : sc;
            }
            sa[mi][ct][j] = sc;
            lm = fmaxf(lm, sc);
          }
          rowlm[mi][j] = lm;
          over = over || (lm > mrun[mi][j] + 8.f);
        }
      }
      if (__any(over)){
#pragma unroll
        for (int mi = 0; mi < 2; ++mi)
#pragma unroll
          for (int j = 0; j < 4; ++j){
            float mx = rowlm[mi][j];
#pragma unroll
            for (int d = 1; d < 16; d <<= 1) mx = fmaxf(mx, __shfl_xor(mx, d, 16));
            const float mnew = fmaxf(mrun[mi][j], mx);
            const float corr = exp2f(mrun[mi][j] - mnew);
            mrun[mi][j] = mnew; lrun[mi][j] *= corr;
#pragma unroll
            for (int dt = 0; dt < 8; ++dt) cacc[mi][dt][j] *= corr;
          }
      }
#pragma unroll
      for (int mi = 0; mi < 2; ++mi)
#pragma unroll
        for (int j = 0; j < 4; ++j){
          float psum = 0.f;
#pragma unroll
          for (int ct = 0; ct < 4; ++ct){
            const float p = exp2f(sa[mi][ct][j] - mrun[mi][j]);
            sa[mi][ct][j] = p; psum += p;
          }
          lrun[mi][j] += psum;
        }

#pragma unroll
      for (int mi = 0; mi < 2; ++mi)
#pragma unroll
        for (int ct = 0; ct < 4; ++ct)
#pragma unroll
          for (int j = 0; j < 4; ++j){
            const int row = mi*16 + l4*4 + j, col = ct*16 + l15;
            p_lds[w][row*64 + ((col >> 3) ^ (row & 7))*8 + (col & 7)] = f2bf(sa[mi][ct][j]);
          }

      __builtin_amdgcn_s_setprio(1);
#pragma unroll
      for (int kk2 = 0; kk2 < 2; ++kk2){
        const int kb = kk2*4 + l4;
        short8 pa0 = *(const short8*)&p_lds[w][l15*64 + ((kb ^ (l15 & 7))*8)];
        short8 pa1 = *(const short8*)&p_lds[w][(16 + l15)*64 + ((kb ^ (l15 & 7))*8)];
#pragma unroll
        for (int dt = 0; dt < 8; ++dt){
          const int vr = dt*16 + l15;
          short8 vf = *(const short8*)&v_lds[cur][vr*64 + ((kb ^ (vr & 7))*8)];
          cacc[0][dt] = MFMA16(pa0, vf, cacc[0][dt]);
          cacc[1][dt] = MFMA16(pa1, vf, cacc[1][dt]);
        }
      }
      __builtin_amdgcn_s_setprio(0);
    }

    if (t + 1 < nt){ __syncthreads(); cur ^= 1; }
  }

#pragma unroll
  for (int mi = 0; mi < 2; ++mi){
    float inv[4];
#pragma unroll
    for (int j = 0; j < 4; ++j){
      float lt = lrun[mi][j];
#pragma unroll
      for (int d = 1; d < 16; d <<= 1) lt += __shfl_xor(lt, d, 16);
      inv[j] = 1.f / lt;
    }
#pragma unroll
    for (int dt = 0; dt < 8; ++dt)
#pragma unroll
      for (int j = 0; j < 4; ++j){
        const int s = qt*128 + w*32 + mi*16 + l4*4 + j;
        const int d = dt*16 + l15;
        ctx[((size_t)(bb*2048 + s))*2048 + hh*128 + d] = f2bf(cacc[mi][dt][j] * inv[j]);
      }
  }
}

// ---------------- launch ----------------
extern "C" void kernel_launch(void* const* d_in, const int* in_sizes, int n_in,
                              void* d_out, int out_size, void* d_ws, size_t ws_size,
                              hipStream_t stream) {
  const float* x  = (const float*)d_in[0];
  const float* wq = (const float*)d_in[1];
  const float* wk = (const float*)d_in[2];
  const float* wv = (const float*)d_in[3];
  const float* wo = (const float*)d_in[4];
  const float* bo = (const float*)d_in[5];
  const float* g1 = (const float*)d_in[6];
  const float* s1 = (const float*)d_in[7];
  const float* g2 = (const float*)d_in[8];
  const float* s2 = (const float*)d_in[9];
  const float* w1 = (const float*)d_in[10];
  const float* b1 = (const float*)d_in[11];
  const float* w2 = (const float*)d_in[12];
  const float* b2 = (const float*)d_in[13];
  float* out = (float*)d_out;
  char* ws = (char*)d_ws;

  // workspace layout (bytes)
  ushort* wqkvT = (ushort*)(ws + 0);         // [6144][2048] + woT contiguous after
  ushort* woT = (ushort*)(ws + 25165824);
  ushort* w1T = (ushort*)(ws + 33554432);    // [8192][2048]
  ushort* w2T = (ushort*)(ws + 67108864);    // [2048][8192]
  ushort* h1  = (ushort*)(ws + 100663296);   // [4096][2048]
  ushort* qb  = (ushort*)(ws + 117440512);   // [32][2048][128]; k, v^T follow
  ushort* kb  = (ushort*)(ws + 134217728);   // [32][2048][128]
  ushort* vtb = (ushort*)(ws + 150994944);   // [32][128][2048] (V^T, by QKV epi)
  ushort* ctxb= (ushort*)(ws + 184549376);   // [4096][2048]
  float*  x2  = (float*)(ws + 201326592);    // [4096][2048] fp32
  ushort* h2  = (ushort*)(ws + 234881024);   // [4096][2048]
  ushort* ffb = (ushort*)(ws + 117440512);   // [4096][8192] aliases q/k/vt

  // weights -> bf16 transposed
  wconv4<<<dim3(64, 64, 4), 256, 0, stream>>>(wq, wk, wv, wo, wqkvT);
  wconv_ffn<<<dim3(256, 64, 2), 256, 0, stream>>>(w1, w2, w1T, w2T);

  // LN1
  ln_kernel<<<4096, 256, 0, stream>>>(x, g1, s1, h1);

  // fused QKV: q (pre-scaled by SCALE*log2e), k -> [b,h,s,d]; V -> V^T
  gemm_bt<0,0><<<32*48, 256, 0, stream>>>(h1, wqkvT, 6144, 2048, qb, nullptr, nullptr);

  // attention (4-wave blocks; XCD-pinned bh; work-paired qt order)
  attn_kernel<<<512, 256, 0, stream>>>(qb, kb, vtb, ctxb);

  // out proj + residual -> x2 (fp32)
  gemm_bt<1,0><<<32*16, 256, 0, stream>>>(ctxb, woT, 2048, 2048, x2, x, bo);

  // LN2
  ln_kernel<<<4096, 256, 0, stream>>>(x2, g2, s2, h2);

  // FFN
  gemm_bt<2,0><<<32*64, 256, 0, stream>>>(h2, w1T, 8192, 2048, ffb, nullptr, b1);
  // FFN2: K=8192 -> L2-sized A working set (2 panels/XCD, super-rounds)
  gemm_bt<1,1><<<32*16, 256, 0, stream>>>(ffb, w2T, 2048, 8192, out, x2, b2);

  (void)in_sizes; (void)n_in; (void)out_size; (void)ws_size;
}

// Round 14
// 668.323 us; speedup vs baseline: 1.0119x; 1.0009x over previous
//
#include <hip/hip_runtime.h>
#include <hip/hip_bf16.h>
#include <cstdint>

// ---------------- problem constants ----------------
// B=2, S=2048, D=2048, H=16, HD=128, FF=8192; M = B*S = 4096 rows
constexpr float SCALE_QK = 0.02209708691207961f; // 1/sqrt(2048)
constexpr float LOG2E    = 1.4426950408889634f;

using short8 = __attribute__((ext_vector_type(8))) short;
using f32x4  = __attribute__((ext_vector_type(4))) float;
using ushort4v = __attribute__((ext_vector_type(4))) ushort;

#define MFMA16(a,b,c) __builtin_amdgcn_mfma_f32_16x16x32_bf16((a),(b),(c),0,0,0)

__device__ __forceinline__ ushort f2bf(float f){
  uint32_t u = __builtin_bit_cast(uint32_t, f);
  u += 0x7fffu + ((u >> 16) & 1u);      // RNE
  return (ushort)(u >> 16);
}

// async global->LDS, 16B per lane; LDS dest is wave-uniform base + lane*16
__device__ __forceinline__ void gload_lds16(const void* g, void* l){
  __builtin_amdgcn_global_load_lds(
      (const __attribute__((address_space(1))) void*)g,
      (__attribute__((address_space(3))) void*)l, 16, 0, 0);
}

// ---------------- LayerNorm: fp32 row -> bf16 row ----------------
__global__ __launch_bounds__(256) void ln_kernel(
    const float* __restrict__ x, const float* __restrict__ g,
    const float* __restrict__ sh, ushort* __restrict__ out){
  const int row = blockIdx.x, t = threadIdx.x;
  const float* xr = x + (size_t)row*2048 + t*8;
  float v[8];
  *(float4*)&v[0] = *(const float4*)(xr);
  *(float4*)&v[4] = *(const float4*)(xr + 4);
  float s = 0.f, sq = 0.f;
#pragma unroll
  for (int i = 0; i < 8; ++i){ s += v[i]; sq += v[i]*v[i]; }
#pragma unroll
  for (int d = 1; d < 64; d <<= 1){ s += __shfl_xor(s, d, 64); sq += __shfl_xor(sq, d, 64); }
  __shared__ float red[8];
  const int w = t >> 6, lane = t & 63;
  if (lane == 0){ red[w] = s; red[4 + w] = sq; }
  __syncthreads();
  s  = red[0] + red[1] + red[2] + red[3];
  sq = red[4] + red[5] + red[6] + red[7];
  const float mean = s * (1.f/2048.f);
  const float inv  = rsqrtf(sq * (1.f/2048.f) - mean*mean + 1e-5f);
  union { ushort u[8]; uint4 v4; } o;
#pragma unroll
  for (int i = 0; i < 8; ++i){
    int j = t*8 + i;
    o.u[i] = f2bf((v[i] - mean) * inv * g[j] + sh[j]);
  }
  *(uint4*)(out + (size_t)row*2048 + t*8) = o.v4;
}

// merged: four 2048x2048 fp32 [K][N] -> bf16 [N][K] (outputs contiguous)
__global__ __launch_bounds__(256) void wconv4(
    const float* __restrict__ w0, const float* __restrict__ w1p,
    const float* __restrict__ w2p, const float* __restrict__ w3p,
    ushort* __restrict__ out){
  __shared__ ushort tile[32][34];
  const int tx = threadIdx.x & 31, ty = threadIdx.x >> 5;
  const int n0 = blockIdx.x * 32, k0 = blockIdx.y * 32, z = blockIdx.z;
  const float* in = (z == 0) ? w0 : (z == 1) ? w1p : (z == 2) ? w2p : w3p;
  ushort* o = out + (size_t)z * 4194304;
#pragma unroll
  for (int r = 0; r < 4; ++r){
    int kk = ty + r*8;
    tile[kk][tx] = f2bf(in[(size_t)(k0 + kk)*2048 + n0 + tx]);
  }
  __syncthreads();
#pragma unroll
  for (int r = 0; r < 4; ++r){
    int nn = ty + r*8;
    o[(size_t)(n0 + nn)*2048 + k0 + tx] = tile[tx][nn];
  }
}

// merged FFN weight convert: z=0 -> w1 (K=2048,N=8192), z=1 -> w2 (K=8192,N=2048)
__global__ __launch_bounds__(256) void wconv_ffn(
    const float* __restrict__ w1, const float* __restrict__ w2,
    ushort* __restrict__ w1T, ushort* __restrict__ w2T){
  __shared__ ushort tile[32][34];
  const int tx = threadIdx.x & 31, ty = threadIdx.x >> 5;
  const int z = blockIdx.z;
  const float* in; ushort* out; int K, N, n0, k0;
  if (z == 0){ in = w1; out = w1T; K = 2048; N = 8192;
               n0 = blockIdx.x * 32; k0 = blockIdx.y * 32; }
  else       { in = w2; out = w2T; K = 8192; N = 2048;
               n0 = blockIdx.y * 32; k0 = blockIdx.x * 32; }
#pragma unroll
  for (int r = 0; r < 4; ++r){
    int kk = ty + r*8;
    tile[kk][tx] = f2bf(in[(size_t)(k0 + kk)*N + n0 + tx]);
  }
  __syncthreads();
#pragma unroll
  for (int r = 0; r < 4; ++r){
    int nn = ty + r*8;
    out[(size_t)(n0 + nn)*K + k0 + tx] = tile[tx][nn];
  }
}

// ---------------- 128x128 m97-structure GEMM ----------------
// MODE 0: mb = xcd*4 + (j&3); MODE 1: 2 m-panels/XCD super-rounds (FFN2).
// EPI 0: fused-QKV, LDS-staged coalesced epilogue; q pre-scaled by
//        SCALE_QK*LOG2E; V -> V^T.  EPI 1: fp32 = resid + bias + acc;
// EPI 2: bf16 = gelu_tanh(acc + bias)
template<int EPI, int MODE>
__global__ __launch_bounds__(256) void gemm_bt(
    const ushort* __restrict__ A, const ushort* __restrict__ Bt,
    int N, int K, void* __restrict__ outp,
    const float* __restrict__ resid, const float* __restrict__ bias){
  __shared__ ushort lds[2][128*64];
  const int tid = threadIdx.x, lane = tid & 63, wid = tid >> 6;
  const int wr = wid >> 1, wc = wid & 1;
  const int l15 = lane & 15, l4 = lane >> 4;

  const int bid = blockIdx.x;
  const int xcd = bid & 7, j = bid >> 3;
  int mb, nb;
  if constexpr (MODE == 0){
    mb = xcd*4 + (j & 3); nb = j >> 2;
  } else {
    const int jm = j & 1, rest = j >> 1;
    nb = rest & 15;
    mb = (rest >> 4)*16 + xcd*2 + jm;
  }
  const int m0 = mb * 128, n0 = nb * 128;

  f32x4 acc[4][4];
#pragma unroll
  for (int mi = 0; mi < 4; ++mi)
#pragma unroll
    for (int ni = 0; ni < 4; ++ni) acc[mi][ni] = (f32x4){0.f,0.f,0.f,0.f};

  const ushort* Abase = A  + (size_t)m0*K;
  const ushort* Bbase = Bt + (size_t)n0*K;

  const int NTk = K >> 6;
  for (int kt = 0; kt < NTk; ++kt){
    if (kt) __syncthreads();
#pragma unroll
    for (int i = 0; i < 4; ++i){
      const int chunk = (i*4 + wid)*64 + lane;
      const int row = chunk >> 3;
      const int c8  = (chunk & 7) ^ (row & 7);
      const size_t goff = (size_t)row*K + (size_t)kt*64 + c8*8;
      gload_lds16(Abase + goff, (ushort*)&lds[0][0] + (size_t)(i*4 + wid)*512);
      gload_lds16(Bbase + goff, (ushort*)&lds[1][0] + (size_t)(i*4 + wid)*512);
    }
    __syncthreads();

#pragma unroll
    for (int kk = 0; kk < 2; ++kk){
      short8 af[4], bf[4];
      const int kb = kk*4 + l4;
#pragma unroll
      for (int i = 0; i < 4; ++i){
        const int rA = wr*64 + i*16 + l15;
        af[i] = *(const short8*)&lds[0][rA*64 + ((kb ^ (rA & 7))*8)];
        const int rB = wc*64 + i*16 + l15;
        bf[i] = *(const short8*)&lds[1][rB*64 + ((kb ^ (rB & 7))*8)];
      }
#pragma unroll
      for (int mi = 0; mi < 4; ++mi)
#pragma unroll
        for (int ni = 0; ni < 4; ++ni)
          acc[mi][ni] = MFMA16(af[mi], bf[ni], acc[mi][ni]);
    }
  }

  if constexpr (EPI == 0){
    __syncthreads();
    ushort* tile = (ushort*)&lds[0][0];
    const int which = n0 >> 11;
    const int hh = (n0 & 2047) >> 7;
    const int bb = m0 >> 11, srow0 = m0 & 2047;
    if (which != 2){
      const float qs = (which == 0) ? SCALE_QK * LOG2E : 1.0f; // log2-domain q
#pragma unroll
      for (int mi = 0; mi < 4; ++mi)
#pragma unroll
        for (int ni = 0; ni < 4; ++ni){
          const int rl = wr*64 + mi*16 + l4*4;
          const int cl = wc*64 + ni*16 + l15;
#pragma unroll
          for (int j2 = 0; j2 < 4; ++j2)
            tile[(rl + j2)*128 + cl] = f2bf(acc[mi][ni][j2] * qs);
        }
      __syncthreads();
      ushort* dst = (ushort*)outp + (size_t)which*8388608 +
                    ((size_t)(bb*16 + hh)*2048 + srow0)*128;
#pragma unroll
      for (int i = 0; i < 8; ++i){
        const int c = i*256 + tid, row = c >> 4, d8 = (c & 15)*8;
        *(uint4*)(dst + (size_t)row*128 + d8) = *(const uint4*)&tile[row*128 + d8];
      }
    } else {
#pragma unroll
      for (int mi = 0; mi < 4; ++mi)
#pragma unroll
        for (int ni = 0; ni < 4; ++ni){
          const int rl = wr*64 + mi*16 + l4*4;
          const int cl = wc*64 + ni*16 + l15;
          ushort4v o;
#pragma unroll
          for (int j2 = 0; j2 < 4; ++j2) o[j2] = f2bf(acc[mi][ni][j2]);
          *(ushort4v*)&tile[cl*128 + rl] = o;
        }
      __syncthreads();
      ushort* dst = (ushort*)outp + (size_t)2*8388608 +
                    (size_t)(bb*16 + hh)*262144 + srow0;
#pragma unroll
      for (int i = 0; i < 8; ++i){
        const int c = i*256 + tid, drow = c >> 4, s8 = (c & 15)*8;
        *(uint4*)(dst + (size_t)drow*2048 + s8) = *(const uint4*)&tile[drow*128 + s8];
      }
    }
  } else {
#pragma unroll
    for (int mi = 0; mi < 4; ++mi){
#pragma unroll
      for (int ni = 0; ni < 4; ++ni){
        const int rloc = wr*64 + mi*16 + l4*4;
        const int col  = n0 + wc*64 + ni*16 + l15;
#pragma unroll
        for (int j2 = 0; j2 < 4; ++j2){
          const int m = m0 + rloc + j2;
          float v = acc[mi][ni][j2];
          if constexpr (EPI == 1){
            ((float*)outp)[(size_t)m*N + col] = resid[(size_t)m*N + col] + bias[col] + v;
          } else {
            const float xx = v + bias[col];
            const float z  = 0.7978845608f*(xx + 0.044715f*xx*xx*xx);
            const float t  = __expf(-2.f*fabsf(z));
            const float th = (1.f - t)/(1.f + t);
            const float gl = 0.5f*xx*(1.f + copysignf(th, xx));
            ((ushort*)outp)[(size_t)m*N + col] = f2bf(gl);
          }
        }
      }
    }
  }
}

// ---------------- causal flash attention, QBLK=128, KVBLK=128 ----------------
// 512 thr = 8 waves x 16 q-rows. KV tiles of 128 halve the tile count ->
// half the barriers / per-tile serialization vs KVBLK=64 at identical MFMA
// and exp work. K[2][128x128] + V^T[2][128x128] dbuf via global_load_lds
// (pre-swizzled src); per-wave P[16][64] reused across the two kv-halves
// (wave-private; DS ops are in-order per wave -> WAR safe). 144 KB LDS ->
// 1 block/CU (8 waves). Lazy defer-max, log2-domain softmax, setprio kept.
// Diagonal mask collapses to the single t==qt tile.
__global__ __launch_bounds__(512, 1) void attn_kernel(
    const ushort* __restrict__ q, const ushort* __restrict__ k,
    const ushort* __restrict__ vt, ushort* __restrict__ ctx){
  __shared__ ushort k_lds[2][128*128];  // 64 KB  [kv][d]
  __shared__ ushort v_lds[2][128*128];  // 64 KB  [d][kv]
  __shared__ ushort p_lds[8][16*64];    // 16 KB  per-wave P (half-width, 2-pass)
  const int tid = threadIdx.x, lane = tid & 63, w = tid >> 6;
  const int l15 = lane & 15, l4 = lane >> 4;
  const int id = blockIdx.x;
  const int bh = id & 31;
  const int r  = id >> 5;
  const int qt = (r < 8) ? (15 - r) : (r - 8);
  const int bb = bh >> 4, hh = bh & 15;
  const ushort* kbase = k  + (size_t)bh * 262144;
  const ushort* vbase = vt + (size_t)bh * 262144;

  // Q fragments: wave w rows qt*128 + w*16 + l15
  short8 qf[4];
  {
    const int s = qt*128 + w*16 + l15;
    const ushort* qr = q + ((size_t)bh*2048 + s)*128 + l4*8;
#pragma unroll
    for (int kk = 0; kk < 4; ++kk) qf[kk] = *(const short8*)(qr + kk*32);
  }

  f32x4 cacc[8];
#pragma unroll
  for (int dt = 0; dt < 8; ++dt) cacc[dt] = (f32x4){0.f,0.f,0.f,0.f};
  float mrun[4], lrun[4];
#pragma unroll
  for (int j = 0; j < 4; ++j){ mrun[j] = -1e30f; lrun[j] = 0.f; }

  // stage K tile (128x128) + V^T tile (128x128): 2048 chunks each, 4/thread
  auto stage = [&](int buf, int t){
    const ushort* ksrc = kbase + (size_t)t*16384;
#pragma unroll
    for (int i = 0; i < 4; ++i){
      const int chunk = i*512 + tid;
      const int kr = chunk >> 4;
      const int c8 = (chunk & 15) ^ (kr & 7);
      gload_lds16(ksrc + (size_t)kr*128 + c8*8, &k_lds[buf][(size_t)chunk*8]);
    }
#pragma unroll
    for (int i = 0; i < 4; ++i){
      const int chunk = i*512 + tid;
      const int vr = chunk >> 4;
      const int c8 = (chunk & 15) ^ (vr & 7);
      gload_lds16(vbase + (size_t)vr*2048 + t*128 + c8*8, &v_lds[buf][(size_t)chunk*8]);
    }
  };

  const int nt = qt + 1;
  stage(0, 0);
  __syncthreads();
  int cur = 0;
  for (int t = 0; t < nt; ++t){
    if (t + 1 < nt) stage(cur ^ 1, t + 1);   // async prefetch next K/V tile

    // QK^T: sa[ct] over 8 col-tiles of 16 kv
    f32x4 sa[8];
#pragma unroll
    for (int ct = 0; ct < 8; ++ct) sa[ct] = (f32x4){0.f,0.f,0.f,0.f};
    __builtin_amdgcn_s_setprio(1);
#pragma unroll
    for (int kk = 0; kk < 4; ++kk){
#pragma unroll
      for (int ct = 0; ct < 8; ++ct){
        const int kr = ct*16 + l15;
        short8 kf = *(const short8*)&k_lds[cur][kr*128 + (((kk*4 + l4) ^ (kr & 7))*8)];
        sa[ct] = MFMA16(qf[kk], kf, sa[ct]);
      }
    }
    __builtin_amdgcn_s_setprio(0);

    const bool anymask = (t == qt);
    // lane-local masked max per row; wave-wide lazy trigger
    float rowlm[4];
    bool over = false;
#pragma unroll
    for (int j = 0; j < 4; ++j){
      const int qa = qt*128 + w*16 + l4*4 + j;
      float lm = -1e30f;
#pragma unroll
      for (int ct = 0; ct < 8; ++ct){
        float sc = sa[ct][j];
        if (anymask){
          const int ka = t*128 + ct*16 + l15;
          sc = (ka > qa) ? -1e30f : sc;
        }
        sa[ct][j] = sc;
        lm = fmaxf(lm, sc);
      }
      rowlm[j] = lm;
      over = over || (lm > mrun[j] + 8.f);
    }
    if (__any(over)){  // rare: full rowmax reduce + rescale
#pragma unroll
      for (int j = 0; j < 4; ++j){
        float mx = rowlm[j];
#pragma unroll
        for (int d = 1; d < 16; d <<= 1) mx = fmaxf(mx, __shfl_xor(mx, d, 16));
        const float mnew = fmaxf(mrun[j], mx);
        const float corr = exp2f(mrun[j] - mnew);
        mrun[j] = mnew; lrun[j] *= corr;
#pragma unroll
        for (int dt = 0; dt < 8; ++dt) cacc[dt][j] *= corr;
      }
    }
    // P = exp2(s - m), row sums (lane-local)
#pragma unroll
    for (int j = 0; j < 4; ++j){
      float psum = 0.f;
#pragma unroll
      for (int ct = 0; ct < 8; ++ct){
        const float p = exp2f(sa[ct][j] - mrun[j]);
        sa[ct][j] = p; psum += p;
      }
      lrun[j] += psum;
    }

    // PV in two kv-halves, reusing the per-wave P buffer
    __builtin_amdgcn_s_setprio(1);
#pragma unroll
    for (int half = 0; half < 2; ++half){
      // write P cols [half*64, half*64+64) -> p_lds[w] ([16][64] swizzled)
#pragma unroll
      for (int ct2 = 0; ct2 < 4; ++ct2){
        const int ct = half*4 + ct2;
#pragma unroll
        for (int j = 0; j < 4; ++j){
          const int row = l4*4 + j, col = ct2*16 + l15;
          p_lds[w][row*64 + ((col >> 3) ^ (row & 7))*8 + (col & 7)] = f2bf(sa[ct][j]);
        }
      }
#pragma unroll
      for (int kk2 = 0; kk2 < 2; ++kk2){
        const int kb = kk2*4 + l4;            // chunk within the 64-kv half
        short8 pa = *(const short8*)&p_lds[w][l15*64 + ((kb ^ (l15 & 7))*8)];
#pragma unroll
        for (int dt = 0; dt < 8; ++dt){
          const int vr = dt*16 + l15;
          const int g = half*8 + kb;          // global kv chunk in tile
          short8 vf = *(const short8*)&v_lds[cur][vr*128 + ((g ^ (vr & 7))*8)];
          cacc[dt] = MFMA16(pa, vf, cacc[dt]);
        }
      }
    }
    __builtin_amdgcn_s_setprio(0);

    if (t + 1 < nt){ __syncthreads(); cur ^= 1; }
  }

  // epilogue: divide by row sums, write ctx[(b*2048+s)][h*128+d]
  float inv[4];
#pragma unroll
  for (int j = 0; j < 4; ++j){
    float lt = lrun[j];
#pragma unroll
    for (int d = 1; d < 16; d <<= 1) lt += __shfl_xor(lt, d, 16);
    inv[j] = 1.f / lt;
  }
#pragma unroll
  for (int dt = 0; dt < 8; ++dt)
#pragma unroll
    for (int j = 0; j < 4; ++j){
      const int s = qt*128 + w*16 + l4*4 + j;
      const int d = dt*16 + l15;
      ctx[((size_t)(bb*2048 + s))*2048 + hh*128 + d] = f2bf(cacc[dt][j] * inv[j]);
    }
}

// ---------------- launch ----------------
extern "C" void kernel_launch(void* const* d_in, const int* in_sizes, int n_in,
                              void* d_out, int out_size, void* d_ws, size_t ws_size,
                              hipStream_t stream) {
  const float* x  = (const float*)d_in[0];
  const float* wq = (const float*)d_in[1];
  const float* wk = (const float*)d_in[2];
  const float* wv = (const float*)d_in[3];
  const float* wo = (const float*)d_in[4];
  const float* bo = (const float*)d_in[5];
  const float* g1 = (const float*)d_in[6];
  const float* s1 = (const float*)d_in[7];
  const float* g2 = (const float*)d_in[8];
  const float* s2 = (const float*)d_in[9];
  const float* w1 = (const float*)d_in[10];
  const float* b1 = (const float*)d_in[11];
  const float* w2 = (const float*)d_in[12];
  const float* b2 = (const float*)d_in[13];
  float* out = (float*)d_out;
  char* ws = (char*)d_ws;

  // workspace layout (bytes)
  ushort* wqkvT = (ushort*)(ws + 0);         // [6144][2048] + woT contiguous after
  ushort* woT = (ushort*)(ws + 25165824);
  ushort* w1T = (ushort*)(ws + 33554432);    // [8192][2048]
  ushort* w2T = (ushort*)(ws + 67108864);    // [2048][8192]
  ushort* h1  = (ushort*)(ws + 100663296);   // [4096][2048]
  ushort* qb  = (ushort*)(ws + 117440512);   // [32][2048][128]; k, v^T follow
  ushort* kb  = (ushort*)(ws + 134217728);   // [32][2048][128]
  ushort* vtb = (ushort*)(ws + 150994944);   // [32][128][2048] (V^T, by QKV epi)
  ushort* ctxb= (ushort*)(ws + 184549376);   // [4096][2048]
  float*  x2  = (float*)(ws + 201326592);    // [4096][2048] fp32
  ushort* h2  = (ushort*)(ws + 234881024);   // [4096][2048]
  ushort* ffb = (ushort*)(ws + 117440512);   // [4096][8192] aliases q/k/vt

  // weights -> bf16 transposed
  wconv4<<<dim3(64, 64, 4), 256, 0, stream>>>(wq, wk, wv, wo, wqkvT);
  wconv_ffn<<<dim3(256, 64, 2), 256, 0, stream>>>(w1, w2, w1T, w2T);

  // LN1
  ln_kernel<<<4096, 256, 0, stream>>>(x, g1, s1, h1);

  // fused QKV: q (pre-scaled by SCALE*log2e), k -> [b,h,s,d]; V -> V^T
  gemm_bt<0,0><<<32*48, 256, 0, stream>>>(h1, wqkvT, 6144, 2048, qb, nullptr, nullptr);

  // attention (KVBLK=128; XCD-pinned bh; work-paired qt order)
  attn_kernel<<<512, 512, 0, stream>>>(qb, kb, vtb, ctxb);

  // out proj + residual -> x2 (fp32)
  gemm_bt<1,0><<<32*16, 256, 0, stream>>>(ctxb, woT, 2048, 2048, x2, x, bo);

  // LN2
  ln_kernel<<<4096, 256, 0, stream>>>(x2, g2, s2, h2);

  // FFN
  gemm_bt<2,0><<<32*64, 256, 0, stream>>>(h2, w1T, 8192, 2048, ffb, nullptr, b1);
  gemm_bt<1,1><<<32*16, 256, 0, stream>>>(ffb, w2T, 2048, 8192, out, x2, b2);

  (void)in_sizes; (void)n_in; (void)out_size; (void)ws_size;
}

// Round 15
// 666.030 us; speedup vs baseline: 1.0154x; 1.0034x over previous
//
#include <hip/hip_runtime.h>
#include <hip/hip_bf16.h>
#include <cstdint>

// ---------------- problem constants ----------------
// B=2, S=2048, D=2048, H=16, HD=128, FF=8192; M = B*S = 4096 rows
constexpr float SCALE_QK = 0.02209708691207961f; // 1/sqrt(2048)
constexpr float LOG2E    = 1.4426950408889634f;

using short8 = __attribute__((ext_vector_type(8))) short;
using f32x4  = __attribute__((ext_vector_type(4))) float;
using ushort4v = __attribute__((ext_vector_type(4))) ushort;

#define MFMA16(a,b,c) __builtin_amdgcn_mfma_f32_16x16x32_bf16((a),(b),(c),0,0,0)

__device__ __forceinline__ ushort f2bf(float f){
  uint32_t u = __builtin_bit_cast(uint32_t, f);
  u += 0x7fffu + ((u >> 16) & 1u);      // RNE
  return (ushort)(u >> 16);
}

// async global->LDS, 16B per lane; LDS dest is wave-uniform base + lane*16
__device__ __forceinline__ void gload_lds16(const void* g, void* l){
  __builtin_amdgcn_global_load_lds(
      (const __attribute__((address_space(1))) void*)g,
      (__attribute__((address_space(3))) void*)l, 16, 0, 0);
}

// ---------------- LayerNorm: fp32 row -> bf16 row ----------------
__global__ __launch_bounds__(256) void ln_kernel(
    const float* __restrict__ x, const float* __restrict__ g,
    const float* __restrict__ sh, ushort* __restrict__ out){
  const int row = blockIdx.x, t = threadIdx.x;
  const float* xr = x + (size_t)row*2048 + t*8;
  float v[8];
  *(float4*)&v[0] = *(const float4*)(xr);
  *(float4*)&v[4] = *(const float4*)(xr + 4);
  float s = 0.f, sq = 0.f;
#pragma unroll
  for (int i = 0; i < 8; ++i){ s += v[i]; sq += v[i]*v[i]; }
#pragma unroll
  for (int d = 1; d < 64; d <<= 1){ s += __shfl_xor(s, d, 64); sq += __shfl_xor(sq, d, 64); }
  __shared__ float red[8];
  const int w = t >> 6, lane = t & 63;
  if (lane == 0){ red[w] = s; red[4 + w] = sq; }
  __syncthreads();
  s  = red[0] + red[1] + red[2] + red[3];
  sq = red[4] + red[5] + red[6] + red[7];
  const float mean = s * (1.f/2048.f);
  const float inv  = rsqrtf(sq * (1.f/2048.f) - mean*mean + 1e-5f);
  union { ushort u[8]; uint4 v4; } o;
#pragma unroll
  for (int i = 0; i < 8; ++i){
    int j = t*8 + i;
    o.u[i] = f2bf((v[i] - mean) * inv * g[j] + sh[j]);
  }
  *(uint4*)(out + (size_t)row*2048 + t*8) = o.v4;
}

// ---- vectorized 64x64 convert+transpose tile: float4 loads, ushort4 stores ----
// LDS tile stored TRANSPOSED [n][k], pad 68 keeps 8B alignment for vector reads.
__device__ __forceinline__ void wconv_tile64(
    const float* __restrict__ in, ushort* __restrict__ out,
    int K, int N, int k0, int n0, ushort (*tile)[68]){
  const int t = threadIdx.x;
#pragma unroll
  for (int i = 0; i < 4; ++i){
    const int idx = i*256 + t;
    const int kk = idx >> 4, c4 = (idx & 15)*4;
    const float4 v = *(const float4*)&in[(size_t)(k0 + kk)*N + n0 + c4];
    tile[c4+0][kk] = f2bf(v.x); tile[c4+1][kk] = f2bf(v.y);
    tile[c4+2][kk] = f2bf(v.z); tile[c4+3][kk] = f2bf(v.w);
  }
  __syncthreads();
#pragma unroll
  for (int i = 0; i < 4; ++i){
    const int idx = i*256 + t;
    const int nn = idx >> 4, k4 = (idx & 15)*4;
    *(ushort4v*)&out[(size_t)(n0 + nn)*K + k0 + k4] = *(const ushort4v*)&tile[nn][k4];
  }
}

// merged: four 2048x2048 fp32 [K][N] -> bf16 [N][K] (outputs contiguous)
__global__ __launch_bounds__(256) void wconv4(
    const float* __restrict__ w0, const float* __restrict__ w1p,
    const float* __restrict__ w2p, const float* __restrict__ w3p,
    ushort* __restrict__ out){
  __shared__ ushort tile[64][68];
  const int n0 = blockIdx.x * 64, k0 = blockIdx.y * 64, z = blockIdx.z;
  const float* in = (z == 0) ? w0 : (z == 1) ? w1p : (z == 2) ? w2p : w3p;
  wconv_tile64(in, out + (size_t)z * 4194304, 2048, 2048, k0, n0, tile);
}

// merged FFN weight convert: z=0 -> w1 (K=2048,N=8192), z=1 -> w2 (K=8192,N=2048)
__global__ __launch_bounds__(256) void wconv_ffn(
    const float* __restrict__ w1, const float* __restrict__ w2,
    ushort* __restrict__ w1T, ushort* __restrict__ w2T){
  __shared__ ushort tile[64][68];
  const int z = blockIdx.z;
  if (z == 0) wconv_tile64(w1, w1T, 2048, 8192, blockIdx.y*64, blockIdx.x*64, tile);
  else        wconv_tile64(w2, w2T, 8192, 2048, blockIdx.x*64, blockIdx.y*64, tile);
}

// ---------------- 128x128 m97-structure GEMM ----------------
// MODE 0: mb = xcd*4 + (j&3); MODE 1: 2 m-panels/XCD super-rounds (FFN2).
// EPI 0: fused-QKV, LDS-staged coalesced epilogue; q pre-scaled by
//        SCALE_QK*LOG2E; V -> V^T.  EPI 1: fp32 = resid + bias + acc;
// EPI 2: bf16 = gelu_tanh(acc + bias)
template<int EPI, int MODE>
__global__ __launch_bounds__(256) void gemm_bt(
    const ushort* __restrict__ A, const ushort* __restrict__ Bt,
    int N, int K, void* __restrict__ outp,
    const float* __restrict__ resid, const float* __restrict__ bias){
  __shared__ ushort lds[2][128*64];
  const int tid = threadIdx.x, lane = tid & 63, wid = tid >> 6;
  const int wr = wid >> 1, wc = wid & 1;
  const int l15 = lane & 15, l4 = lane >> 4;

  const int bid = blockIdx.x;
  const int xcd = bid & 7, j = bid >> 3;
  int mb, nb;
  if constexpr (MODE == 0){
    mb = xcd*4 + (j & 3); nb = j >> 2;
  } else {
    const int jm = j & 1, rest = j >> 1;
    nb = rest & 15;
    mb = (rest >> 4)*16 + xcd*2 + jm;
  }
  const int m0 = mb * 128, n0 = nb * 128;

  f32x4 acc[4][4];
#pragma unroll
  for (int mi = 0; mi < 4; ++mi)
#pragma unroll
    for (int ni = 0; ni < 4; ++ni) acc[mi][ni] = (f32x4){0.f,0.f,0.f,0.f};

  const ushort* Abase = A  + (size_t)m0*K;
  const ushort* Bbase = Bt + (size_t)n0*K;

  const int NTk = K >> 6;
  for (int kt = 0; kt < NTk; ++kt){
    if (kt) __syncthreads();
#pragma unroll
    for (int i = 0; i < 4; ++i){
      const int chunk = (i*4 + wid)*64 + lane;
      const int row = chunk >> 3;
      const int c8  = (chunk & 7) ^ (row & 7);
      const size_t goff = (size_t)row*K + (size_t)kt*64 + c8*8;
      gload_lds16(Abase + goff, (ushort*)&lds[0][0] + (size_t)(i*4 + wid)*512);
      gload_lds16(Bbase + goff, (ushort*)&lds[1][0] + (size_t)(i*4 + wid)*512);
    }
    __syncthreads();

#pragma unroll
    for (int kk = 0; kk < 2; ++kk){
      short8 af[4], bf[4];
      const int kb = kk*4 + l4;
#pragma unroll
      for (int i = 0; i < 4; ++i){
        const int rA = wr*64 + i*16 + l15;
        af[i] = *(const short8*)&lds[0][rA*64 + ((kb ^ (rA & 7))*8)];
        const int rB = wc*64 + i*16 + l15;
        bf[i] = *(const short8*)&lds[1][rB*64 + ((kb ^ (rB & 7))*8)];
      }
#pragma unroll
      for (int mi = 0; mi < 4; ++mi)
#pragma unroll
        for (int ni = 0; ni < 4; ++ni)
          acc[mi][ni] = MFMA16(af[mi], bf[ni], acc[mi][ni]);
    }
  }

  if constexpr (EPI == 0){
    __syncthreads();
    ushort* tile = (ushort*)&lds[0][0];
    const int which = n0 >> 11;
    const int hh = (n0 & 2047) >> 7;
    const int bb = m0 >> 11, srow0 = m0 & 2047;
    if (which != 2){
      const float qs = (which == 0) ? SCALE_QK * LOG2E : 1.0f; // log2-domain q
#pragma unroll
      for (int mi = 0; mi < 4; ++mi)
#pragma unroll
        for (int ni = 0; ni < 4; ++ni){
          const int rl = wr*64 + mi*16 + l4*4;
          const int cl = wc*64 + ni*16 + l15;
#pragma unroll
          for (int j2 = 0; j2 < 4; ++j2)
            tile[(rl + j2)*128 + cl] = f2bf(acc[mi][ni][j2] * qs);
        }
      __syncthreads();
      ushort* dst = (ushort*)outp + (size_t)which*8388608 +
                    ((size_t)(bb*16 + hh)*2048 + srow0)*128;
#pragma unroll
      for (int i = 0; i < 8; ++i){
        const int c = i*256 + tid, row = c >> 4, d8 = (c & 15)*8;
        *(uint4*)(dst + (size_t)row*128 + d8) = *(const uint4*)&tile[row*128 + d8];
      }
    } else {
#pragma unroll
      for (int mi = 0; mi < 4; ++mi)
#pragma unroll
        for (int ni = 0; ni < 4; ++ni){
          const int rl = wr*64 + mi*16 + l4*4;
          const int cl = wc*64 + ni*16 + l15;
          ushort4v o;
#pragma unroll
          for (int j2 = 0; j2 < 4; ++j2) o[j2] = f2bf(acc[mi][ni][j2]);
          *(ushort4v*)&tile[cl*128 + rl] = o;
        }
      __syncthreads();
      ushort* dst = (ushort*)outp + (size_t)2*8388608 +
                    (size_t)(bb*16 + hh)*262144 + srow0;
#pragma unroll
      for (int i = 0; i < 8; ++i){
        const int c = i*256 + tid, drow = c >> 4, s8 = (c & 15)*8;
        *(uint4*)(dst + (size_t)drow*2048 + s8) = *(const uint4*)&tile[drow*128 + s8];
      }
    }
  } else {
#pragma unroll
    for (int mi = 0; mi < 4; ++mi){
#pragma unroll
      for (int ni = 0; ni < 4; ++ni){
        const int rloc = wr*64 + mi*16 + l4*4;
        const int col  = n0 + wc*64 + ni*16 + l15;
#pragma unroll
        for (int j2 = 0; j2 < 4; ++j2){
          const int m = m0 + rloc + j2;
          float v = acc[mi][ni][j2];
          if constexpr (EPI == 1){
            ((float*)outp)[(size_t)m*N + col] = resid[(size_t)m*N + col] + bias[col] + v;
          } else {
            const float xx = v + bias[col];
            const float z  = 0.7978845608f*(xx + 0.044715f*xx*xx*xx);
            const float t  = __expf(-2.f*fabsf(z));
            const float th = (1.f - t)/(1.f + t);
            const float gl = 0.5f*xx*(1.f + copysignf(th, xx));
            ((ushort*)outp)[(size_t)m*N + col] = f2bf(gl);
          }
        }
      }
    }
  }
}

// ---------------- causal flash attention, QBLK=128, KVBLK=128 (R14) ----------------
__global__ __launch_bounds__(512, 1) void attn_kernel(
    const ushort* __restrict__ q, const ushort* __restrict__ k,
    const ushort* __restrict__ vt, ushort* __restrict__ ctx){
  __shared__ ushort k_lds[2][128*128];  // 64 KB  [kv][d]
  __shared__ ushort v_lds[2][128*128];  // 64 KB  [d][kv]
  __shared__ ushort p_lds[8][16*64];    // 16 KB  per-wave P (half-width, 2-pass)
  const int tid = threadIdx.x, lane = tid & 63, w = tid >> 6;
  const int l15 = lane & 15, l4 = lane >> 4;
  const int id = blockIdx.x;
  const int bh = id & 31;
  const int r  = id >> 5;
  const int qt = (r < 8) ? (15 - r) : (r - 8);
  const int bb = bh >> 4, hh = bh & 15;
  const ushort* kbase = k  + (size_t)bh * 262144;
  const ushort* vbase = vt + (size_t)bh * 262144;

  short8 qf[4];
  {
    const int s = qt*128 + w*16 + l15;
    const ushort* qr = q + ((size_t)bh*2048 + s)*128 + l4*8;
#pragma unroll
    for (int kk = 0; kk < 4; ++kk) qf[kk] = *(const short8*)(qr + kk*32);
  }

  f32x4 cacc[8];
#pragma unroll
  for (int dt = 0; dt < 8; ++dt) cacc[dt] = (f32x4){0.f,0.f,0.f,0.f};
  float mrun[4], lrun[4];
#pragma unroll
  for (int j = 0; j < 4; ++j){ mrun[j] = -1e30f; lrun[j] = 0.f; }

  auto stage = [&](int buf, int t){
    const ushort* ksrc = kbase + (size_t)t*16384;
#pragma unroll
    for (int i = 0; i < 4; ++i){
      const int chunk = i*512 + tid;
      const int kr = chunk >> 4;
      const int c8 = (chunk & 15) ^ (kr & 7);
      gload_lds16(ksrc + (size_t)kr*128 + c8*8, &k_lds[buf][(size_t)chunk*8]);
    }
#pragma unroll
    for (int i = 0; i < 4; ++i){
      const int chunk = i*512 + tid;
      const int vr = chunk >> 4;
      const int c8 = (chunk & 15) ^ (vr & 7);
      gload_lds16(vbase + (size_t)vr*2048 + t*128 + c8*8, &v_lds[buf][(size_t)chunk*8]);
    }
  };

  const int nt = qt + 1;
  stage(0, 0);
  __syncthreads();
  int cur = 0;
  for (int t = 0; t < nt; ++t){
    if (t + 1 < nt) stage(cur ^ 1, t + 1);

    f32x4 sa[8];
#pragma unroll
    for (int ct = 0; ct < 8; ++ct) sa[ct] = (f32x4){0.f,0.f,0.f,0.f};
    __builtin_amdgcn_s_setprio(1);
#pragma unroll
    for (int kk = 0; kk < 4; ++kk){
#pragma unroll
      for (int ct = 0; ct < 8; ++ct){
        const int kr = ct*16 + l15;
        short8 kf = *(const short8*)&k_lds[cur][kr*128 + (((kk*4 + l4) ^ (kr & 7))*8)];
        sa[ct] = MFMA16(qf[kk], kf, sa[ct]);
      }
    }
    __builtin_amdgcn_s_setprio(0);

    const bool anymask = (t == qt);
    float rowlm[4];
    bool over = false;
#pragma unroll
    for (int j = 0; j < 4; ++j){
      const int qa = qt*128 + w*16 + l4*4 + j;
      float lm = -1e30f;
#pragma unroll
      for (int ct = 0; ct < 8; ++ct){
        float sc = sa[ct][j];
        if (anymask){
          const int ka = t*128 + ct*16 + l15;
          sc = (ka > qa) ? -1e30f : sc;
        }
        sa[ct][j] = sc;
        lm = fmaxf(lm, sc);
      }
      rowlm[j] = lm;
      over = over || (lm > mrun[j] + 8.f);
    }
    if (__any(over)){
#pragma unroll
      for (int j = 0; j < 4; ++j){
        float mx = rowlm[j];
#pragma unroll
        for (int d = 1; d < 16; d <<= 1) mx = fmaxf(mx, __shfl_xor(mx, d, 16));
        const float mnew = fmaxf(mrun[j], mx);
        const float corr = exp2f(mrun[j] - mnew);
        mrun[j] = mnew; lrun[j] *= corr;
#pragma unroll
        for (int dt = 0; dt < 8; ++dt) cacc[dt][j] *= corr;
      }
    }
#pragma unroll
    for (int j = 0; j < 4; ++j){
      float psum = 0.f;
#pragma unroll
      for (int ct = 0; ct < 8; ++ct){
        const float p = exp2f(sa[ct][j] - mrun[j]);
        sa[ct][j] = p; psum += p;
      }
      lrun[j] += psum;
    }

    __builtin_amdgcn_s_setprio(1);
#pragma unroll
    for (int half = 0; half < 2; ++half){
#pragma unroll
      for (int ct2 = 0; ct2 < 4; ++ct2){
        const int ct = half*4 + ct2;
#pragma unroll
        for (int j = 0; j < 4; ++j){
          const int row = l4*4 + j, col = ct2*16 + l15;
          p_lds[w][row*64 + ((col >> 3) ^ (row & 7))*8 + (col & 7)] = f2bf(sa[ct][j]);
        }
      }
#pragma unroll
      for (int kk2 = 0; kk2 < 2; ++kk2){
        const int kb = kk2*4 + l4;
        short8 pa = *(const short8*)&p_lds[w][l15*64 + ((kb ^ (l15 & 7))*8)];
#pragma unroll
        for (int dt = 0; dt < 8; ++dt){
          const int vr = dt*16 + l15;
          const int g = half*8 + kb;
          short8 vf = *(const short8*)&v_lds[cur][vr*128 + ((g ^ (vr & 7))*8)];
          cacc[dt] = MFMA16(pa, vf, cacc[dt]);
        }
      }
    }
    __builtin_amdgcn_s_setprio(0);

    if (t + 1 < nt){ __syncthreads(); cur ^= 1; }
  }

  float inv[4];
#pragma unroll
  for (int j = 0; j < 4; ++j){
    float lt = lrun[j];
#pragma unroll
    for (int d = 1; d < 16; d <<= 1) lt += __shfl_xor(lt, d, 16);
    inv[j] = 1.f / lt;
  }
#pragma unroll
  for (int dt = 0; dt < 8; ++dt)
#pragma unroll
    for (int j = 0; j < 4; ++j){
      const int s = qt*128 + w*16 + l4*4 + j;
      const int d = dt*16 + l15;
      ctx[((size_t)(bb*2048 + s))*2048 + hh*128 + d] = f2bf(cacc[dt][j] * inv[j]);
    }
}

// ---------------- launch ----------------
extern "C" void kernel_launch(void* const* d_in, const int* in_sizes, int n_in,
                              void* d_out, int out_size, void* d_ws, size_t ws_size,
                              hipStream_t stream) {
  const float* x  = (const float*)d_in[0];
  const float* wq = (const float*)d_in[1];
  const float* wk = (const float*)d_in[2];
  const float* wv = (const float*)d_in[3];
  const float* wo = (const float*)d_in[4];
  const float* bo = (const float*)d_in[5];
  const float* g1 = (const float*)d_in[6];
  const float* s1 = (const float*)d_in[7];
  const float* g2 = (const float*)d_in[8];
  const float* s2 = (const float*)d_in[9];
  const float* w1 = (const float*)d_in[10];
  const float* b1 = (const float*)d_in[11];
  const float* w2 = (const float*)d_in[12];
  const float* b2 = (const float*)d_in[13];
  float* out = (float*)d_out;
  char* ws = (char*)d_ws;

  // workspace layout (bytes)
  ushort* wqkvT = (ushort*)(ws + 0);         // [6144][2048] + woT contiguous after
  ushort* woT = (ushort*)(ws + 25165824);
  ushort* w1T = (ushort*)(ws + 33554432);    // [8192][2048]
  ushort* w2T = (ushort*)(ws + 67108864);    // [2048][8192]
  ushort* h1  = (ushort*)(ws + 100663296);   // [4096][2048]
  ushort* qb  = (ushort*)(ws + 117440512);   // [32][2048][128]; k, v^T follow
  ushort* kb  = (ushort*)(ws + 134217728);   // [32][2048][128]
  ushort* vtb = (ushort*)(ws + 150994944);   // [32][128][2048] (V^T, by QKV epi)
  ushort* ctxb= (ushort*)(ws + 184549376);   // [4096][2048]
  float*  x2  = (float*)(ws + 201326592);    // [4096][2048] fp32
  ushort* h2  = (ushort*)(ws + 234881024);   // [4096][2048]
  ushort* ffb = (ushort*)(ws + 117440512);   // [4096][8192] aliases q/k/vt

  // weights -> bf16 transposed (vectorized: float4 loads, ushort4 stores)
  wconv4<<<dim3(32, 32, 4), 256, 0, stream>>>(wq, wk, wv, wo, wqkvT);
  wconv_ffn<<<dim3(128, 32, 2), 256, 0, stream>>>(w1, w2, w1T, w2T);

  // LN1
  ln_kernel<<<4096, 256, 0, stream>>>(x, g1, s1, h1);

  // fused QKV: q (pre-scaled by SCALE*log2e), k -> [b,h,s,d]; V -> V^T
  gemm_bt<0,0><<<32*48, 256, 0, stream>>>(h1, wqkvT, 6144, 2048, qb, nullptr, nullptr);

  // attention (KVBLK=128; XCD-pinned bh; work-paired qt order)
  attn_kernel<<<512, 512, 0, stream>>>(qb, kb, vtb, ctxb);

  // out proj + residual -> x2 (fp32)
  gemm_bt<1,0><<<32*16, 256, 0, stream>>>(ctxb, woT, 2048, 2048, x2, x, bo);

  // LN2
  ln_kernel<<<4096, 256, 0, stream>>>(x2, g2, s2, h2);

  // FFN
  gemm_bt<2,0><<<32*64, 256, 0, stream>>>(h2, w1T, 8192, 2048, ffb, nullptr, b1);
  gemm_bt<1,1><<<32*16, 256, 0, stream>>>(ffb, w2T, 2048, 8192, out, x2, b2);

  (void)in_sizes; (void)n_in; (void)out_size; (void)ws_size;
}